// Round 10
// baseline (306.795 us; speedup 1.0000x reference)
//
#include <hip/hip_runtime.h>

typedef unsigned long long u64;
typedef unsigned int u32;

#define NTOK 131072
#define DIMS 1024
#define NT   256

// d_ws layout (bytes):
//   [0, 65536)            sigT   : u32[8][256][8]  transposed signature planes
//   [65536, 66560)        flags  : int[256]        sig-has-zero flags
//   [66560, 132096)       zflagw : int[16384]      per-8-token-wave x-zero flags
//   [262144, +16.78MB)    masks1 : u32[NTOK][32]   plane1 = (x>0)   bits
//   [262144+16.78MB, ...) masks2 : u32[NTOK][32]   plane2 = (x>=0)  bits
#define SIGT_OFF   0
#define FLAGS_OFF  65536
#define ZFLAG_OFF  66560
#define MASK1_OFF  262144
#define MASK2_OFF  (MASK1_OFF + (size_t)NTOK * 128)

// ---------------------------------------------------------------------------
// Kernel A: signatures as 2 bit-planes, TRANSPOSED chunk layout (R9-verified):
//   sigT[kc*2048 + t*8 + j] (u32); kc 0..3 = plane1 (s>0), kc 4..7 = plane2
//   (s>0 | s==0).  dist = popc(p1x^p1s) + popc(p2x^p2s)  [complements cancel]
//   = 2*popc(p1x^p1s) when no zeros anywhere (fast path).
// ---------------------------------------------------------------------------
__global__ void sig_kernel(const float* __restrict__ base,
                           const float* __restrict__ deltas,
                           u32* __restrict__ sigT,
                           int* __restrict__ flags)
{
    const int t    = blockIdx.x;
    const int lane = threadIdx.x;
    u64 zany = 0;
    #pragma unroll
    for (int c = 0; c < 4; ++c) {
        #pragma unroll
        for (int j = 0; j < 4; ++j) {
            const int d = c * 256 + lane * 4 + j;
            const float b  = base[d];
            const float dl = (t > 0) ? deltas[(size_t)(t - 1) * DIMS + d] : 0.0f;
            const bool use_d = (dl != 0.0f);
            const bool p1 = use_d ? (dl > 0.0f) : (b > 0.0f);
            const bool p2 = use_d ? (dl > 0.0f) : (b >= 0.0f);  // pos|zero
            const u64 b1 = __ballot(p1);
            const u64 b2 = __ballot(p2);
            zany |= (b1 ^ b2);
            if (lane == 0) {
                const int w32 = 2 * (c * 4 + j);
                const int kc = w32 >> 3, j8 = w32 & 7;
                sigT[kc * 2048 + t * 8 + j8]           = (u32)b1;
                sigT[kc * 2048 + t * 8 + j8 + 1]       = (u32)(b1 >> 32);
                sigT[(kc + 4) * 2048 + t * 8 + j8]     = (u32)b2;
                sigT[(kc + 4) * 2048 + t * 8 + j8 + 1] = (u32)(b2 >> 32);
            }
        }
    }
    if (lane == 0) flags[t] = (zany != 0) ? 1 : 0;
}

// ---------------------------------------------------------------------------
// Kernel B: mask build — pure streaming, no LDS, no barrier, max occupancy.
// Wave w handles 8 tokens; per token: 4 coalesced float4 loads, 8 ballots
// (plane1 = v>0, plane2 = v>=0), lane0 stores 2x16B per c-iter per plane.
// Token word mapping identical to sig_kernel (u64 word W = c*4+j).
// zflagw[global wave id] = any x==0 among these 8 tokens (p1^p2).
// ---------------------------------------------------------------------------
__global__ __launch_bounds__(256)
void mask_kernel(const float* __restrict__ x,
                 u32* __restrict__ masks1,
                 u32* __restrict__ masks2,
                 int* __restrict__ zflagw)
{
    const int lane = threadIdx.x & 63;
    const int w    = threadIdx.x >> 6;
    const int wid  = blockIdx.x * 4 + w;
    const int tok0 = wid * 8;

    u64 zany = 0;
    for (int tk = 0; tk < 8; ++tk) {
        const int tok = tok0 + tk;
        const float4* xr = (const float4*)(x + (size_t)tok * DIMS);
        u64* m1 = (u64*)(masks1 + (size_t)tok * 32);
        u64* m2 = (u64*)(masks2 + (size_t)tok * 32);
        #pragma unroll
        for (int c = 0; c < 4; ++c) {
            const float4 v = xr[c * 64 + lane];
            const u64 a0 = __ballot(v.x > 0.0f); const u64 b0 = __ballot(v.x >= 0.0f);
            const u64 a1 = __ballot(v.y > 0.0f); const u64 b1 = __ballot(v.y >= 0.0f);
            const u64 a2 = __ballot(v.z > 0.0f); const u64 b2 = __ballot(v.z >= 0.0f);
            const u64 a3 = __ballot(v.w > 0.0f); const u64 b3 = __ballot(v.w >= 0.0f);
            zany |= (a0 ^ b0) | (a1 ^ b1) | (a2 ^ b2) | (a3 ^ b3);
            if (lane == 0) {
                ulonglong2 s;
                s.x = a0; s.y = a1; *(ulonglong2*)(m1 + c * 4)     = s;
                s.x = a2; s.y = a3; *(ulonglong2*)(m1 + c * 4 + 2) = s;
                s.x = b0; s.y = b1; *(ulonglong2*)(m2 + c * 4)     = s;
                s.x = b2; s.y = b3; *(ulonglong2*)(m2 + c * 4 + 2) = s;
            }
        }
    }
    if (lane == 0) zflagw[wid] = (zany != 0) ? 1 : 0;
}

// ---------------------------------------------------------------------------
// Kernel C: distances + argmin. Block = token-group g (64 tokens) x 4 waves;
// wave q owns tile quarter [64q, 64q+64) as two halves of 32.
// Lane = token. Chunk-major inner loop (R8-verified): per chunk kc, lane
// loads 32B of its token's mask (L1-resident, shared across the 4 waves),
// inner unrolled 32 tiles against contiguous transposed signatures.
// Fast path (no zeros): plane1 only, dist = 2*acc. No barrier until the
// final argmin combine.
// ---------------------------------------------------------------------------
__global__ __launch_bounds__(256, 4)
void dist_kernel(const u32* __restrict__ sigT,
                 const int* __restrict__ flags,
                 const int* __restrict__ zflagw,
                 const u32* __restrict__ masks1,
                 const u32* __restrict__ masks2,
                 float* __restrict__ idx_out,
                 float* __restrict__ dist_out)
{
    __shared__ int lkey[4][64];

    const int lane = threadIdx.x & 63;
    const int q    = threadIdx.x >> 6;
    const int g    = blockIdx.x;
    const int tok0 = g * 64;

    // fast/slow decision (wave-uniform)
    const int fs = flags[lane] | flags[64 + lane] | flags[128 + lane] | flags[192 + lane];
    const bool sig_zero = __any(fs != 0);
    const int zf = zflagw[g * 8 + (lane & 7)];
    const bool x_zero = __any(zf != 0);
    const bool fast = !(sig_zero || x_zero);

    const int wbase = __builtin_amdgcn_readfirstlane(q * 64);
    const u32* __restrict__ mrow1 = masks1 + (size_t)(tok0 + lane) * 32;
    const u32* __restrict__ mrow2 = masks2 + (size_t)(tok0 + lane) * 32;

    int bestkey = 0x7fffffff;

    #pragma unroll
    for (int h = 0; h < 2; ++h) {
        const int tbase = wbase + h * 32;
        u32 acc[32];
        #pragma unroll
        for (int t = 0; t < 32; ++t) acc[t] = 0;

#define CHUNK(kc, mrow, plane_off) { \
        const uint4 ma = *(const uint4*)(mrow + (kc) * 8); \
        const uint4 mb = *(const uint4*)(mrow + (kc) * 8 + 4); \
        const u32* __restrict__ sp = sigT + ((kc) + (plane_off)) * 2048 + tbase * 8; \
        _Pragma("unroll") \
        for (int t = 0; t < 32; ++t) { \
            const u32* __restrict__ s8 = sp + t * 8; \
            acc[t] += __popc(ma.x ^ s8[0]) + __popc(ma.y ^ s8[1]) \
                    + __popc(ma.z ^ s8[2]) + __popc(ma.w ^ s8[3]) \
                    + __popc(mb.x ^ s8[4]) + __popc(mb.y ^ s8[5]) \
                    + __popc(mb.z ^ s8[6]) + __popc(mb.w ^ s8[7]); \
        } \
    }

        int shift;
        if (fast) {
            CHUNK(0, mrow1, 0) CHUNK(1, mrow1, 0) CHUNK(2, mrow1, 0) CHUNK(3, mrow1, 0)
            shift = 1;                 // dist = 2 * acc
        } else {
            CHUNK(0, mrow1, 0) CHUNK(1, mrow1, 0) CHUNK(2, mrow1, 0) CHUNK(3, mrow1, 0)
            CHUNK(0, mrow2, 4) CHUNK(1, mrow2, 4) CHUNK(2, mrow2, 4) CHUNK(3, mrow2, 4)
            shift = 0;                 // dist = acc(p1) + acc(p2)
        }
#undef CHUNK

        #pragma unroll
        for (int t = 0; t < 32; ++t)
            bestkey = min(bestkey, ((int)(acc[t] << shift) << 8) | (tbase + t));

        float* drow = dist_out + (size_t)(tok0 + lane) * NT + tbase;
        #pragma unroll
        for (int qq = 0; qq < 8; ++qq) {
            float4 dv;
            dv.x = (float)(acc[4 * qq + 0] << shift); dv.y = (float)(acc[4 * qq + 1] << shift);
            dv.z = (float)(acc[4 * qq + 2] << shift); dv.w = (float)(acc[4 * qq + 3] << shift);
            *(float4*)(drow + 4 * qq) = dv;
        }
    }

    // cross-wave argmin combine (single cheap barrier)
    lkey[q][lane] = bestkey;
    __syncthreads();
    if (q == 0) {
        const int k = min(min(lkey[0][lane], lkey[1][lane]),
                          min(lkey[2][lane], lkey[3][lane]));
        idx_out[tok0 + lane] = (float)(k & 255);
    }
}

extern "C" void kernel_launch(void* const* d_in, const int* in_sizes, int n_in,
                              void* d_out, int out_size, void* d_ws, size_t ws_size,
                              hipStream_t stream)
{
    const float* x      = (const float*)d_in[0];
    const float* base   = (const float*)d_in[1];
    const float* deltas = (const float*)d_in[2];

    char* ws = (char*)d_ws;
    u32* sigT    = (u32*)(ws + SIGT_OFF);
    int* flags   = (int*)(ws + FLAGS_OFF);
    int* zflagw  = (int*)(ws + ZFLAG_OFF);
    u32* masks1  = (u32*)(ws + MASK1_OFF);
    u32* masks2  = (u32*)(ws + MASK2_OFF);

    float* idx_out  = (float*)d_out;                 // N floats (tile indices)
    float* dist_out = idx_out + NTOK;                // N*T floats

    sig_kernel<<<NT, 64, 0, stream>>>(base, deltas, sigT, flags);
    mask_kernel<<<NTOK / 32, 256, 0, stream>>>(x, masks1, masks2, zflagw);
    dist_kernel<<<NTOK / 64, 256, 0, stream>>>(sigT, flags, zflagw, masks1, masks2,
                                               idx_out, dist_out);
}

// Round 12
// 228.449 us; speedup vs baseline: 1.3430x; 1.3430x over previous
//
#include <hip/hip_runtime.h>

typedef unsigned long long u64;
typedef unsigned int u32;

#define NTOK 131072
#define DIMS 1024
#define NT   256

// d_ws layout:
//   [0, 32768)      sigF : u32[256][32]  plane1 (s>0), 128B/tile row
//   [32768, 65536)  sigS : u32[256][32]  plane2 (s>0 | s==0)
//   [65536, 66560)  flags: int[256]      sig-has-zero flags
#define SIGF_OFF  0
#define SIGS_OFF  32768
#define FLAGS_OFF 65536

// ---------------------------------------------------------------------------
// Kernel A: signatures as 2 bit-planes, compact row-major:
//   sigF[t*32 + 2W+h], W = c*4+j (u64 word), h = lo/hi half.  (R11 bug: rows
//   are 32 u32 = 1024 bits, NOT 16.)
// dist = popc(p1x^p1s) + popc(p2x^p2s)   [complement planes cancel in xor]
//      = 2*popc(p1x^p1s) when no exact zeros anywhere (fast path).
// ---------------------------------------------------------------------------
__global__ void sig_kernel(const float* __restrict__ base,
                           const float* __restrict__ deltas,
                           u32* __restrict__ sigF,
                           u32* __restrict__ sigS,
                           int* __restrict__ flags)
{
    const int t    = blockIdx.x;
    const int lane = threadIdx.x;
    u64 zany = 0;
    #pragma unroll
    for (int c = 0; c < 4; ++c) {
        #pragma unroll
        for (int j = 0; j < 4; ++j) {
            const int d = c * 256 + lane * 4 + j;
            const float b  = base[d];
            const float dl = (t > 0) ? deltas[(size_t)(t - 1) * DIMS + d] : 0.0f;
            const bool use_d = (dl != 0.0f);
            const bool p1 = use_d ? (dl > 0.0f) : (b > 0.0f);
            const bool p2 = use_d ? (dl > 0.0f) : (b >= 0.0f);
            const u64 b1 = __ballot(p1);
            const u64 b2 = __ballot(p2);
            zany |= (b1 ^ b2);
            if (lane == 0) {
                const int W = c * 4 + j;
                sigF[t * 32 + 2 * W]     = (u32)b1;
                sigF[t * 32 + 2 * W + 1] = (u32)(b1 >> 32);
                sigS[t * 32 + 2 * W]     = (u32)b2;
                sigS[t * 32 + 2 * W + 1] = (u32)(b2 >> 32);
            }
        }
    }
    if (lane == 0) flags[t] = (zany != 0) ? 1 : 0;
}

// ---------------------------------------------------------------------------
// Kernel B (fused). Block = 64 tokens x 4 waves; wave q owns tiles
// [64q, 64q+64); lane = token.
// Phase 1 (R1-verified): wave q ballot-packs tokens [16q,16q+16) into LDS,
//   both planes, u32[64][36] (144B stride: 16B-aligned, bank-spread).
// Gather: lane pulls its token's 32 plane1 words into VGPRs (one-time).
// Phase 2 tile-major: per tile, 128B uniform s_load of the sigF row +
//   32 xor + 32 bcnt-acc (4 independent accumulators); per-lane running
//   argmin; distances buffered 16/lane -> 4 back-to-back float4 stores.
// Slow path (exact zeros, ~never): adds plane2/sigS term, algebra exact.
// ---------------------------------------------------------------------------
__global__ __launch_bounds__(256, 4)
void dist_kernel(const float* __restrict__ x,
                 const u32* __restrict__ sigF,
                 const u32* __restrict__ sigS,
                 const int* __restrict__ flags,
                 float* __restrict__ idx_out,
                 float* __restrict__ dist_out)
{
    __shared__ u32 lm1[64][36];   // 9216 B  plane1 rows
    __shared__ u32 lm2[64][36];   // 9216 B  plane2 rows
    __shared__ int zfl[4];
    __shared__ int lkey[4][64];

    const int lane = threadIdx.x & 63;
    const int q    = threadIdx.x >> 6;
    const int tok0 = blockIdx.x * 64;

    const int fs = flags[lane] | flags[64 + lane] | flags[128 + lane] | flags[192 + lane];
    const bool sig_zero = __any(fs != 0);

    // ---- phase 1: ballot-pack 16 tokens per wave into LDS, both planes ----
    u64 zany = 0;
    for (int tk = 0; tk < 16; ++tk) {
        const int tok = q * 16 + tk;
        const float4* xr = (const float4*)(x + (size_t)(tok0 + tok) * DIMS);
        #pragma unroll
        for (int c = 0; c < 4; ++c) {
            const float4 v = xr[c * 64 + lane];
            const u64 a0 = __ballot(v.x > 0.0f); const u64 b0 = __ballot(v.x >= 0.0f);
            const u64 a1 = __ballot(v.y > 0.0f); const u64 b1 = __ballot(v.y >= 0.0f);
            const u64 a2 = __ballot(v.z > 0.0f); const u64 b2 = __ballot(v.z >= 0.0f);
            const u64 a3 = __ballot(v.w > 0.0f); const u64 b3 = __ballot(v.w >= 0.0f);
            zany |= (a0 ^ b0) | (a1 ^ b1) | (a2 ^ b2) | (a3 ^ b3);
            if (lane == 0) {
                uint4 s;
                s.x = (u32)a0; s.y = (u32)(a0 >> 32); s.z = (u32)a1; s.w = (u32)(a1 >> 32);
                *(uint4*)&lm1[tok][c * 8]     = s;
                s.x = (u32)a2; s.y = (u32)(a2 >> 32); s.z = (u32)a3; s.w = (u32)(a3 >> 32);
                *(uint4*)&lm1[tok][c * 8 + 4] = s;
                s.x = (u32)b0; s.y = (u32)(b0 >> 32); s.z = (u32)b1; s.w = (u32)(b1 >> 32);
                *(uint4*)&lm2[tok][c * 8]     = s;
                s.x = (u32)b2; s.y = (u32)(b2 >> 32); s.z = (u32)b3; s.w = (u32)(b3 >> 32);
                *(uint4*)&lm2[tok][c * 8 + 4] = s;
            }
        }
    }
    if (lane == 0) zfl[q] = (zany != 0) ? 1 : 0;
    __syncthreads();

    const bool fast = !sig_zero && !(zfl[0] | zfl[1] | zfl[2] | zfl[3]);

    // ---- gather this lane's token plane1 row (32 u32) into VGPRs ----
    u32 m1[32];
    {
        const uint4* r = (const uint4*)&lm1[lane][0];
        #pragma unroll
        for (int i = 0; i < 8; ++i) {
            const uint4 v = r[i];
            m1[4 * i + 0] = v.x; m1[4 * i + 1] = v.y;
            m1[4 * i + 2] = v.z; m1[4 * i + 3] = v.w;
        }
    }

    const int qb = __builtin_amdgcn_readfirstlane(q * 64);
    int bestkey = 0x7fffffff;
    float* drow = dist_out + (size_t)(tok0 + lane) * NT + qb;

    if (fast) {
        for (int tg = 0; tg < 64; tg += 16) {
            float dbuf[16];
            #pragma unroll
            for (int u = 0; u < 16; ++u) {
                const int t = qb + tg + u;
                const u32* __restrict__ sr = sigF + (size_t)t * 32;
                int s0 = 0, s1 = 0, s2 = 0, s3 = 0;
                #pragma unroll
                for (int k = 0; k < 32; k += 4) {
                    s0 += __popc(m1[k + 0] ^ sr[k + 0]);
                    s1 += __popc(m1[k + 1] ^ sr[k + 1]);
                    s2 += __popc(m1[k + 2] ^ sr[k + 2]);
                    s3 += __popc(m1[k + 3] ^ sr[k + 3]);
                }
                const int dist = 2 * ((s0 + s1) + (s2 + s3));
                bestkey = min(bestkey, (dist << 8) | t);
                dbuf[u] = (float)dist;
            }
            #pragma unroll
            for (int qq = 0; qq < 4; ++qq) {
                float4 dv;
                dv.x = dbuf[4 * qq + 0]; dv.y = dbuf[4 * qq + 1];
                dv.z = dbuf[4 * qq + 2]; dv.w = dbuf[4 * qq + 3];
                *(float4*)(drow + tg + 4 * qq) = dv;
            }
        }
    } else {
        u32 m2[32];
        {
            const uint4* r = (const uint4*)&lm2[lane][0];
            #pragma unroll
            for (int i = 0; i < 8; ++i) {
                const uint4 v = r[i];
                m2[4 * i + 0] = v.x; m2[4 * i + 1] = v.y;
                m2[4 * i + 2] = v.z; m2[4 * i + 3] = v.w;
            }
        }
        for (int tg = 0; tg < 64; tg += 16) {
            float dbuf[16];
            #pragma unroll
            for (int u = 0; u < 16; ++u) {
                const int t = qb + tg + u;
                const u32* __restrict__ s1p = sigF + (size_t)t * 32;
                const u32* __restrict__ s2p = sigS + (size_t)t * 32;
                int sa = 0, sb = 0;
                #pragma unroll
                for (int k = 0; k < 32; ++k) {
                    sa += __popc(m1[k] ^ s1p[k]);
                    sb += __popc(m2[k] ^ s2p[k]);
                }
                const int dist = sa + sb;
                bestkey = min(bestkey, (dist << 8) | t);
                dbuf[u] = (float)dist;
            }
            #pragma unroll
            for (int qq = 0; qq < 4; ++qq) {
                float4 dv;
                dv.x = dbuf[4 * qq + 0]; dv.y = dbuf[4 * qq + 1];
                dv.z = dbuf[4 * qq + 2]; dv.w = dbuf[4 * qq + 3];
                *(float4*)(drow + tg + 4 * qq) = dv;
            }
        }
    }

    // ---- combine the 4 tile-quarters for argmin ----
    lkey[q][lane] = bestkey;
    __syncthreads();
    if (q == 0) {
        const int k = min(min(lkey[0][lane], lkey[1][lane]),
                          min(lkey[2][lane], lkey[3][lane]));
        idx_out[tok0 + lane] = (float)(k & 255);
    }
}

extern "C" void kernel_launch(void* const* d_in, const int* in_sizes, int n_in,
                              void* d_out, int out_size, void* d_ws, size_t ws_size,
                              hipStream_t stream)
{
    const float* x      = (const float*)d_in[0];
    const float* base   = (const float*)d_in[1];
    const float* deltas = (const float*)d_in[2];

    char* ws = (char*)d_ws;
    u32* sigF  = (u32*)(ws + SIGF_OFF);
    u32* sigS  = (u32*)(ws + SIGS_OFF);
    int* flags = (int*)(ws + FLAGS_OFF);

    float* idx_out  = (float*)d_out;                 // N floats (tile indices)
    float* dist_out = idx_out + NTOK;                // N*T floats

    sig_kernel<<<NT, 64, 0, stream>>>(base, deltas, sigF, sigS, flags);
    dist_kernel<<<NTOK / 64, 256, 0, stream>>>(x, sigF, sigS, flags, idx_out, dist_out);
}